// Round 1
// baseline (3499.305 us; speedup 1.0000x reference)
//
#include <hip/hip_runtime.h>
#include <hip/hip_bf16.h>

#define ALPHA 0.2f

typedef unsigned short u16;
typedef __attribute__((ext_vector_type(8))) short bf16x8_t;   // MFMA A/B frag (8 bf16)
typedef __attribute__((ext_vector_type(4))) float f32x4_t;    // MFMA C/D frag
typedef __attribute__((ext_vector_type(4))) unsigned short u16x4;

__device__ __forceinline__ u16 f2bf_rne(float f) {
  unsigned u = __float_as_uint(f);
  u += 0x7fffu + ((u >> 16) & 1u);        // round-to-nearest-even
  return (u16)(u >> 16);
}

__device__ __forceinline__ float bf2f(u16 u) {
  return __uint_as_float(((unsigned)u) << 16);
}

// ---------------- K0: convert fc_w / k_w / v_w to bf16 into ws ----------------
__global__ __launch_bounds__(256) void convert_weights(
    const float* __restrict__ fcw, const float* __restrict__ kw,
    const float* __restrict__ vw, u16* __restrict__ dst) {
  int arr = blockIdx.x >> 8;                                   // 0..2
  int i = (((blockIdx.x & 255) << 8) + threadIdx.x) << 2;      // elem idx, x4
  const float* src = (arr == 0) ? fcw : (arr == 1) ? kw : vw;
  float4 v = *(const float4*)(src + i);
  u16x4 r;
  r.x = f2bf_rne(v.x); r.y = f2bf_rne(v.y); r.z = f2bf_rne(v.z); r.w = f2bf_rne(v.w);
  *(u16x4*)(dst + arr * 262144 + i) = r;
}

// ---------------- K1: xh = lrelu(x@fc_w^T + fc_b); query = xh@q_w^T + q_b ------
// fp32 exact path; 8 batches per block, thread t computes h = t and t+256.
__global__ __launch_bounds__(256) void xh_query(
    const float* __restrict__ x, const float* __restrict__ fcw,
    const float* __restrict__ fcb, const float* __restrict__ qw,
    const float* __restrict__ qb, float* __restrict__ xh_ws,
    float* __restrict__ q_ws) {
  __shared__ float xs[8][512];
  __shared__ float xhs[8][512];
  const int tid = threadIdx.x;
  const size_t b0 = (size_t)blockIdx.x * 8;

  const float4* xp = (const float4*)(x + b0 * 512);
  float4* xs4 = (float4*)xs;
  for (int i = tid; i < 1024; i += 256) xs4[i] = xp[i];
  __syncthreads();

  const int h1 = tid, h2 = tid + 256;
  {
    float acc1[8] = {}, acc2[8] = {};
    for (int d = 0; d < 512; d += 4) {
      float4 w1 = *(const float4*)(fcw + h1 * 512 + d);
      float4 w2 = *(const float4*)(fcw + h2 * 512 + d);
#pragma unroll
      for (int bb = 0; bb < 8; bb++) {
        float4 xv = *(const float4*)&xs[bb][d];
        acc1[bb] = fmaf(w1.x, xv.x, fmaf(w1.y, xv.y, fmaf(w1.z, xv.z, fmaf(w1.w, xv.w, acc1[bb]))));
        acc2[bb] = fmaf(w2.x, xv.x, fmaf(w2.y, xv.y, fmaf(w2.z, xv.z, fmaf(w2.w, xv.w, acc2[bb]))));
      }
    }
    float bb1 = fcb[h1], bb2 = fcb[h2];
#pragma unroll
    for (int bb = 0; bb < 8; bb++) {
      float v1 = acc1[bb] + bb1; v1 = v1 > 0.f ? v1 : ALPHA * v1;
      float v2 = acc2[bb] + bb2; v2 = v2 > 0.f ? v2 : ALPHA * v2;
      xhs[bb][h1] = v1; xhs[bb][h2] = v2;
      xh_ws[(b0 + bb) * 512 + h1] = v1; xh_ws[(b0 + bb) * 512 + h2] = v2;
    }
  }
  __syncthreads();
  {
    float acc1[8] = {}, acc2[8] = {};
    for (int d = 0; d < 512; d += 4) {
      float4 w1 = *(const float4*)(qw + h1 * 512 + d);
      float4 w2 = *(const float4*)(qw + h2 * 512 + d);
#pragma unroll
      for (int bb = 0; bb < 8; bb++) {
        float4 xv = *(const float4*)&xhs[bb][d];
        acc1[bb] = fmaf(w1.x, xv.x, fmaf(w1.y, xv.y, fmaf(w1.z, xv.z, fmaf(w1.w, xv.w, acc1[bb]))));
        acc2[bb] = fmaf(w2.x, xv.x, fmaf(w2.y, xv.y, fmaf(w2.z, xv.z, fmaf(w2.w, xv.w, acc2[bb]))));
      }
    }
    float bb1 = qb[h1], bb2 = qb[h2];
#pragma unroll
    for (int bb = 0; bb < 8; bb++) {
      q_ws[(b0 + bb) * 512 + h1] = acc1[bb] + bb1;
      q_ws[(b0 + bb) * 512 + h2] = acc2[bb] + bb2;
    }
  }
}

// ---------------- K2: fused yh-GEMM -> vec-GEMM -> key-GEMM -> softmax/out -----
// One block per b. 8 waves; wave owns 64 columns (h) x 128 rows (l).
// LDS: yh[128][520] bf16 (pad 520 -> row-to-row shift of 4 banks, 2-way = free).
#define YH_STRIDE 520
__global__ __launch_bounds__(512, 2) void attn_main(
    const float* __restrict__ y, const u16* __restrict__ fcw,
    const u16* __restrict__ kw, const u16* __restrict__ vw,
    const float* __restrict__ fcb, const float* __restrict__ kb,
    const float* __restrict__ vb, const float* __restrict__ xh_ws,
    const float* __restrict__ q_ws, float* __restrict__ out) {
  extern __shared__ u16 yh[];   // [128][YH_STRIDE]
  const int b = blockIdx.x;
  const int tid = threadIdx.x;
  const int w = tid >> 6;
  const int lane = tid & 63;
  const int lc = lane & 15;     // A-row sub / B-col sub / C-col
  const int lq = lane >> 4;     // quad: k-offset group, C-row group
  const int colBase = w << 6;
  const int kko = lq << 3;

  int col[4];
#pragma unroll
  for (int nt = 0; nt < 4; nt++) col[nt] = colBase + nt * 16 + lc;

  const f32x4_t fzero = {0.f, 0.f, 0.f, 0.f};
  f32x4_t acc[8][4];

  // ======== phase 1: yh = lrelu(y_b @ fc_w^T + fc_b), bf16 -> LDS ========
#pragma unroll
  for (int mt = 0; mt < 8; mt++)
#pragma unroll
    for (int nt = 0; nt < 4; nt++) acc[mt][nt] = fzero;

  const float* yb = y + (size_t)b * (128 * 512);
  for (int k0 = 0; k0 < 512; k0 += 32) {
    const int kk = k0 + kko;
    bf16x8_t bf[4];
#pragma unroll
    for (int nt = 0; nt < 4; nt++)
      bf[nt] = *(const bf16x8_t*)(fcw + col[nt] * 512 + kk);
#pragma unroll
    for (int mt = 0; mt < 8; mt++) {
      const float* p = yb + (mt * 16 + lc) * 512 + kk;
      float4 u0 = *(const float4*)p;
      float4 u1 = *(const float4*)(p + 4);
      union { bf16x8_t v; __hip_bfloat162 h[4]; } cv;
      cv.h[0] = __float22bfloat162_rn(make_float2(u0.x, u0.y));
      cv.h[1] = __float22bfloat162_rn(make_float2(u0.z, u0.w));
      cv.h[2] = __float22bfloat162_rn(make_float2(u1.x, u1.y));
      cv.h[3] = __float22bfloat162_rn(make_float2(u1.z, u1.w));
#pragma unroll
      for (int nt = 0; nt < 4; nt++)
        acc[mt][nt] = __builtin_amdgcn_mfma_f32_16x16x32_bf16(cv.v, bf[nt], acc[mt][nt], 0, 0, 0);
    }
  }
#pragma unroll
  for (int nt = 0; nt < 4; nt++) {
    float fb = fcb[col[nt]];
#pragma unroll
    for (int mt = 0; mt < 8; mt++) {
#pragma unroll
      for (int r = 0; r < 4; r++) {
        int row = mt * 16 + lq * 4 + r;
        float v = acc[mt][nt][r] + fb;
        v = v > 0.f ? v : ALPHA * v;
        yh[row * YH_STRIDE + col[nt]] = f2bf_rne(v);
      }
    }
  }
  __syncthreads();

  // ======== phase 2a: vec = yh @ v_w^T + v_b; keep lrelu(vec) as packed bf16 ====
#pragma unroll
  for (int mt = 0; mt < 8; mt++)
#pragma unroll
    for (int nt = 0; nt < 4; nt++) acc[mt][nt] = fzero;

  for (int k0 = 0; k0 < 512; k0 += 32) {
    const int kk = k0 + kko;
    bf16x8_t bf[4];
#pragma unroll
    for (int nt = 0; nt < 4; nt++)
      bf[nt] = *(const bf16x8_t*)(vw + col[nt] * 512 + kk);
    bf16x8_t af[8];
#pragma unroll
    for (int mt = 0; mt < 8; mt++)
      af[mt] = *(const bf16x8_t*)(yh + (mt * 16 + lc) * YH_STRIDE + kk);
#pragma unroll
    for (int mt = 0; mt < 8; mt++)
#pragma unroll
      for (int nt = 0; nt < 4; nt++)
        acc[mt][nt] = __builtin_amdgcn_mfma_f32_16x16x32_bf16(af[mt], bf[nt], acc[mt][nt], 0, 0, 0);
  }

  unsigned lv[8][4][2];  // lrelu(vec) packed bf16x2, same (mt,nt,r) element order as acc
#pragma unroll
  for (int nt = 0; nt < 4; nt++) {
    float vbias = vb[col[nt]];
#pragma unroll
    for (int mt = 0; mt < 8; mt++) {
      float v0 = acc[mt][nt][0] + vbias; v0 = v0 > 0.f ? v0 : ALPHA * v0;
      float v1 = acc[mt][nt][1] + vbias; v1 = v1 > 0.f ? v1 : ALPHA * v1;
      float v2 = acc[mt][nt][2] + vbias; v2 = v2 > 0.f ? v2 : ALPHA * v2;
      float v3 = acc[mt][nt][3] + vbias; v3 = v3 > 0.f ? v3 : ALPHA * v3;
      lv[mt][nt][0] = (unsigned)f2bf_rne(v0) | ((unsigned)f2bf_rne(v1) << 16);
      lv[mt][nt][1] = (unsigned)f2bf_rne(v2) | ((unsigned)f2bf_rne(v3) << 16);
    }
  }

  // ======== phase 2b: key GEMM, then fused att/softmax/weighted-sum/out ========
#pragma unroll
  for (int mt = 0; mt < 8; mt++)
#pragma unroll
    for (int nt = 0; nt < 4; nt++) acc[mt][nt] = fzero;

  for (int k0 = 0; k0 < 512; k0 += 32) {
    const int kk = k0 + kko;
    bf16x8_t bf[4];
#pragma unroll
    for (int nt = 0; nt < 4; nt++)
      bf[nt] = *(const bf16x8_t*)(kw + col[nt] * 512 + kk);
    bf16x8_t af[8];
#pragma unroll
    for (int mt = 0; mt < 8; mt++)
      af[mt] = *(const bf16x8_t*)(yh + (mt * 16 + lc) * YH_STRIDE + kk);
#pragma unroll
    for (int mt = 0; mt < 8; mt++)
#pragma unroll
      for (int nt = 0; nt < 4; nt++)
        acc[mt][nt] = __builtin_amdgcn_mfma_f32_16x16x32_bf16(af[mt], bf[nt], acc[mt][nt], 0, 0, 0);
  }

#pragma unroll
  for (int nt = 0; nt < 4; nt++) {
    const float kbias = kb[col[nt]];
    const float qv = q_ws[(size_t)b * 512 + col[nt]];
    // att = (key + k_b) * query ; column softmax over l (128 rows spread over
    // 8 mt-tiles x 4 regs locally, x 4 lane-quads -> xor-shuffle by 16,32)
    float mx = -1e30f;
#pragma unroll
    for (int mt = 0; mt < 8; mt++)
#pragma unroll
      for (int r = 0; r < 4; r++) {
        float t = (acc[mt][nt][r] + kbias) * qv;
        acc[mt][nt][r] = t;
        mx = fmaxf(mx, t);
      }
    mx = fmaxf(mx, __shfl_xor(mx, 16));
    mx = fmaxf(mx, __shfl_xor(mx, 32));
    float s = 0.f, hp = 0.f;
#pragma unroll
    for (int mt = 0; mt < 8; mt++)
#pragma unroll
      for (int r = 0; r < 4; r++) {
        float p = __expf(acc[mt][nt][r] - mx);
        unsigned pk = lv[mt][nt][r >> 1];
        float lvv = bf2f((u16)((r & 1) ? (pk >> 16) : (pk & 0xffffu)));
        s += p;
        hp = fmaf(p, lvv, hp);
      }
    s += __shfl_xor(s, 16);  s += __shfl_xor(s, 32);
    hp += __shfl_xor(hp, 16); hp += __shfl_xor(hp, 32);
    // lrelu is positively homogeneous: sum_l lrelu(vec*e) = sum_l e*lrelu(vec)
    float res = (xh_ws[(size_t)b * 512 + col[nt]] + hp / s) * 0.5f;
    if (lq == 0) out[(size_t)b * 512 + col[nt]] = res;
  }
}

extern "C" void kernel_launch(void* const* d_in, const int* in_sizes, int n_in,
                              void* d_out, int out_size, void* d_ws, size_t ws_size,
                              hipStream_t stream) {
  const float* x   = (const float*)d_in[0];
  const float* y   = (const float*)d_in[1];
  const float* fcw = (const float*)d_in[2];
  const float* fcb = (const float*)d_in[3];
  const float* qw  = (const float*)d_in[4];
  const float* qb  = (const float*)d_in[5];
  const float* kw  = (const float*)d_in[6];
  const float* kb  = (const float*)d_in[7];
  const float* vw  = (const float*)d_in[8];
  const float* vb  = (const float*)d_in[9];
  float* out = (float*)d_out;

  // ws layout: fcw_bf(512KB) kw_bf(512KB) vw_bf(512KB) xh(4MB) query(4MB) = 9.5MB
  u16* fcw_bf = (u16*)d_ws;
  u16* kw_bf  = fcw_bf + 262144;
  u16* vw_bf  = kw_bf + 262144;
  float* xh_ws = (float*)(vw_bf + 262144);
  float* q_ws  = xh_ws + (size_t)2048 * 512;

  convert_weights<<<768, 256, 0, stream>>>(fcw, kw, vw, fcw_bf);
  xh_query<<<256, 256, 0, stream>>>(x, fcw, fcb, qw, qb, xh_ws, q_ws);

  const size_t lds_bytes = 128 * YH_STRIDE * sizeof(u16);  // 133120 B
  hipFuncSetAttribute((const void*)attn_main,
                      hipFuncAttributeMaxDynamicSharedMemorySize, (int)lds_bytes);
  attn_main<<<2048, 512, lds_bytes, stream>>>(y, fcw_bf, kw_bf, vw_bf, fcb, kb, vb,
                                              xh_ws, q_ws, out);
}

// Round 2
// 2544.933 us; speedup vs baseline: 1.3750x; 1.3750x over previous
//
#include <hip/hip_runtime.h>
#include <hip/hip_bf16.h>

#define ALPHA 0.2f

typedef unsigned short u16;
typedef __attribute__((ext_vector_type(8))) short bf16x8_t;   // MFMA A/B frag (8 bf16)
typedef __attribute__((ext_vector_type(4))) float f32x4_t;    // MFMA C/D frag
typedef __attribute__((ext_vector_type(4))) unsigned short u16x4;

__device__ __forceinline__ u16 f2bf_rne(float f) {
  unsigned u = __float_as_uint(f);
  u += 0x7fffu + ((u >> 16) & 1u);        // round-to-nearest-even
  return (u16)(u >> 16);
}

// convert 8 consecutive fp32 -> bf16x8 MFMA fragment
__device__ __forceinline__ bf16x8_t cvt8(const float* __restrict__ p) {
  float4 u0 = *(const float4*)p;
  float4 u1 = *(const float4*)(p + 4);
  union { bf16x8_t v; __hip_bfloat162 h[4]; } cv;
  cv.h[0] = __float22bfloat162_rn(make_float2(u0.x, u0.y));
  cv.h[1] = __float22bfloat162_rn(make_float2(u0.z, u0.w));
  cv.h[2] = __float22bfloat162_rn(make_float2(u1.x, u1.y));
  cv.h[3] = __float22bfloat162_rn(make_float2(u1.z, u1.w));
  return cv.v;
}

__device__ __forceinline__ float lrelu(float v) { return v > 0.f ? v : ALPHA * v; }

// ---------------- K0: convert fc_w / q_w / k_w / v_w to bf16 into ws ----------
__global__ __launch_bounds__(256) void convert_weights(
    const float* __restrict__ fcw, const float* __restrict__ qw,
    const float* __restrict__ kw, const float* __restrict__ vw,
    u16* __restrict__ dst) {
  int arr = blockIdx.x >> 8;                                   // 0..3
  int i = (((blockIdx.x & 255) << 8) + threadIdx.x) << 2;      // elem idx, x4
  const float* src = (arr == 0) ? fcw : (arr == 1) ? qw : (arr == 2) ? kw : vw;
  float4 v = *(const float4*)(src + i);
  u16x4 r;
  r.x = f2bf_rne(v.x); r.y = f2bf_rne(v.y); r.z = f2bf_rne(v.z); r.w = f2bf_rne(v.w);
  *(u16x4*)(dst + (size_t)arr * 262144 + i) = r;
}

#define XH_STRIDE 520

// ---------------- K1: xh = lrelu(x@fc_w^T + fc_b); query = xh@q_w^T + q_b ------
// MFMA version. 16 blocks x 512 threads; block owns 128 batches.
__global__ __launch_bounds__(512) void xh_query(
    const float* __restrict__ x, const u16* __restrict__ fcw_bf,
    const u16* __restrict__ qw_bf, const float* __restrict__ fcb,
    const float* __restrict__ qb, float* __restrict__ xh_ws,
    float* __restrict__ q_ws) {
  extern __shared__ u16 xh[];   // [128][XH_STRIDE] bf16
  const int tid = threadIdx.x;
  const int w = tid >> 6;
  const int lane = tid & 63;
  const int lc = lane & 15;
  const int lq = lane >> 4;
  const int colBase = w << 6;
  const int kko = lq << 3;
  const size_t b0 = (size_t)blockIdx.x * 128;

  const f32x4_t fzero = {0.f, 0.f, 0.f, 0.f};

  // ---- phase A (operand-swapped: A=fc_w rows h, B=x rows l) -> xh[l][h] ----
  {
    f32x4_t acc[4][8];
#pragma unroll
    for (int mt = 0; mt < 4; mt++)
#pragma unroll
      for (int nt = 0; nt < 8; nt++) acc[mt][nt] = fzero;

    const float* xb = x + b0 * 512;
    for (int k0 = 0; k0 < 512; k0 += 32) {
      const int kk = k0 + kko;
      bf16x8_t af[4];
#pragma unroll
      for (int mt = 0; mt < 4; mt++)
        af[mt] = *(const bf16x8_t*)(fcw_bf + (colBase + mt * 16 + lc) * 512 + kk);
#pragma unroll
      for (int nt = 0; nt < 8; nt++) {
        bf16x8_t bv = cvt8(xb + (nt * 16 + lc) * 512 + kk);
#pragma unroll
        for (int mt = 0; mt < 4; mt++)
          acc[mt][nt] = __builtin_amdgcn_mfma_f32_16x16x32_bf16(af[mt], bv, acc[mt][nt], 0, 0, 0);
      }
    }
#pragma unroll
    for (int mt = 0; mt < 4; mt++) {
      const int hbase = colBase + mt * 16 + (lq << 2);
      float4 fb4 = *(const float4*)(fcb + hbase);
#pragma unroll
      for (int nt = 0; nt < 8; nt++) {
        const int l = nt * 16 + lc;
        float v0 = lrelu(acc[mt][nt][0] + fb4.x);
        float v1 = lrelu(acc[mt][nt][1] + fb4.y);
        float v2 = lrelu(acc[mt][nt][2] + fb4.z);
        float v3 = lrelu(acc[mt][nt][3] + fb4.w);
        u16x4 pk;
        pk.x = f2bf_rne(v0); pk.y = f2bf_rne(v1); pk.z = f2bf_rne(v2); pk.w = f2bf_rne(v3);
        *(u16x4*)(xh + l * XH_STRIDE + hbase) = pk;
        float4 fv; fv.x = v0; fv.y = v1; fv.z = v2; fv.w = v3;
        *(float4*)(xh_ws + (b0 + l) * 512 + hbase) = fv;
      }
    }
  }
  __syncthreads();

  // ---- phase B: query = xh @ q_w^T + q_b (A=xh rows l from LDS) ----
  {
    f32x4_t acc[8][4];
#pragma unroll
    for (int mt = 0; mt < 8; mt++)
#pragma unroll
      for (int nt = 0; nt < 4; nt++) acc[mt][nt] = fzero;

    for (int k0 = 0; k0 < 512; k0 += 32) {
      const int kk = k0 + kko;
      bf16x8_t bq[4];
#pragma unroll
      for (int nt = 0; nt < 4; nt++)
        bq[nt] = *(const bf16x8_t*)(qw_bf + (colBase + nt * 16 + lc) * 512 + kk);
#pragma unroll
      for (int mt = 0; mt < 8; mt++) {
        bf16x8_t af = *(const bf16x8_t*)(xh + (mt * 16 + lc) * XH_STRIDE + kk);
#pragma unroll
        for (int nt = 0; nt < 4; nt++)
          acc[mt][nt] = __builtin_amdgcn_mfma_f32_16x16x32_bf16(af, bq[nt], acc[mt][nt], 0, 0, 0);
      }
    }
#pragma unroll
    for (int nt = 0; nt < 4; nt++) {
      const int col = colBase + nt * 16 + lc;
      const float qbias = qb[col];
#pragma unroll
      for (int mt = 0; mt < 8; mt++) {
#pragma unroll
        for (int r = 0; r < 4; r++) {
          const int row = mt * 16 + (lq << 2) + r;
          q_ws[(b0 + row) * 512 + col] = acc[mt][nt][r] + qbias;
        }
      }
    }
  }
}

// ---------------- K2: fused yh-GEMM -> joint vec/key GEMM -> softmax/out -------
// One block per b. 8 waves; wave owns 64 h-columns x 128 l-rows.
#define YH_STRIDE 520
__global__ __launch_bounds__(512) void attn_main(
    const float* __restrict__ y, const u16* __restrict__ fcw_bf,
    const u16* __restrict__ kw_bf, const u16* __restrict__ vw_bf,
    const float* __restrict__ fcb, const float* __restrict__ kb,
    const float* __restrict__ vb, const float* __restrict__ xh_ws,
    const float* __restrict__ q_ws, float* __restrict__ out) {
  extern __shared__ u16 yh[];   // [128][YH_STRIDE] bf16, yh[l][h]
  const int b = blockIdx.x;
  const int tid = threadIdx.x;
  const int w = tid >> 6;
  const int lane = tid & 63;
  const int lc = lane & 15;
  const int lq = lane >> 4;
  const int colBase = w << 6;
  const int kko = lq << 3;

  const f32x4_t fzero = {0.f, 0.f, 0.f, 0.f};

  // ===== phase 1 (operand-swapped): yh[l][h] = lrelu(y_b @ fc_w^T + fc_b) =====
  {
    f32x4_t acc[4][8];   // [h-tile][l-tile]
#pragma unroll
    for (int mt = 0; mt < 4; mt++)
#pragma unroll
      for (int nt = 0; nt < 8; nt++) acc[mt][nt] = fzero;

    const float* yb = y + (size_t)b * (128 * 512);
    for (int k0 = 0; k0 < 512; k0 += 32) {
      const int kk = k0 + kko;
      bf16x8_t af[4];
#pragma unroll
      for (int mt = 0; mt < 4; mt++)
        af[mt] = *(const bf16x8_t*)(fcw_bf + (colBase + mt * 16 + lc) * 512 + kk);
#pragma unroll
      for (int nt = 0; nt < 8; nt++) {
        bf16x8_t bv = cvt8(yb + (nt * 16 + lc) * 512 + kk);
#pragma unroll
        for (int mt = 0; mt < 4; mt++)
          acc[mt][nt] = __builtin_amdgcn_mfma_f32_16x16x32_bf16(af[mt], bv, acc[mt][nt], 0, 0, 0);
      }
    }
    // D[m=h][n=l]: lane holds 4 consecutive h (lq*4+r) for l=nt*16+lc -> b64 store
#pragma unroll
    for (int mt = 0; mt < 4; mt++) {
      const int hbase = colBase + mt * 16 + (lq << 2);
      float4 fb4 = *(const float4*)(fcb + hbase);
#pragma unroll
      for (int nt = 0; nt < 8; nt++) {
        const int l = nt * 16 + lc;
        u16x4 pk;
        pk.x = f2bf_rne(lrelu(acc[mt][nt][0] + fb4.x));
        pk.y = f2bf_rne(lrelu(acc[mt][nt][1] + fb4.y));
        pk.z = f2bf_rne(lrelu(acc[mt][nt][2] + fb4.z));
        pk.w = f2bf_rne(lrelu(acc[mt][nt][3] + fb4.w));
        *(u16x4*)(yh + l * YH_STRIDE + hbase) = pk;
      }
    }
  }
  __syncthreads();

  // ===== phase 2: vec & key GEMMs fused in one k-loop (shared A reads), =====
  // ===== processed in two 32-col halves to bound register pressure      =====
  for (int half = 0; half < 2; half++) {
    const int c0 = colBase + half * 32 + lc;
    const int c1 = c0 + 16;
    f32x4_t av[8][2], ak[8][2];
#pragma unroll
    for (int mt = 0; mt < 8; mt++) {
      av[mt][0] = fzero; av[mt][1] = fzero;
      ak[mt][0] = fzero; ak[mt][1] = fzero;
    }

    for (int k0 = 0; k0 < 512; k0 += 32) {
      const int kk = k0 + kko;
      bf16x8_t bv0 = *(const bf16x8_t*)(vw_bf + c0 * 512 + kk);
      bf16x8_t bv1 = *(const bf16x8_t*)(vw_bf + c1 * 512 + kk);
      bf16x8_t bk0 = *(const bf16x8_t*)(kw_bf + c0 * 512 + kk);
      bf16x8_t bk1 = *(const bf16x8_t*)(kw_bf + c1 * 512 + kk);
#pragma unroll
      for (int mt = 0; mt < 8; mt++) {
        bf16x8_t af = *(const bf16x8_t*)(yh + (mt * 16 + lc) * YH_STRIDE + kk);
        av[mt][0] = __builtin_amdgcn_mfma_f32_16x16x32_bf16(af, bv0, av[mt][0], 0, 0, 0);
        av[mt][1] = __builtin_amdgcn_mfma_f32_16x16x32_bf16(af, bv1, av[mt][1], 0, 0, 0);
        ak[mt][0] = __builtin_amdgcn_mfma_f32_16x16x32_bf16(af, bk0, ak[mt][0], 0, 0, 0);
        ak[mt][1] = __builtin_amdgcn_mfma_f32_16x16x32_bf16(af, bk1, ak[mt][1], 0, 0, 0);
      }
    }

#pragma unroll
    for (int nt = 0; nt < 2; nt++) {
      const int c = (nt == 0) ? c0 : c1;
      const float kbias = kb[c];
      const float vbias = vb[c];
      const float qv = q_ws[(size_t)b * 512 + c];
      float mx = -1e30f;
#pragma unroll
      for (int mt = 0; mt < 8; mt++)
#pragma unroll
        for (int r = 0; r < 4; r++) {
          float t = (ak[mt][nt][r] + kbias) * qv;
          ak[mt][nt][r] = t;
          mx = fmaxf(mx, t);
        }
      mx = fmaxf(mx, __shfl_xor(mx, 16));
      mx = fmaxf(mx, __shfl_xor(mx, 32));
      float s = 0.f, hp = 0.f;
#pragma unroll
      for (int mt = 0; mt < 8; mt++)
#pragma unroll
        for (int r = 0; r < 4; r++) {
          float p = __expf(ak[mt][nt][r] - mx);
          float vv = lrelu(av[mt][nt][r] + vbias);   // lrelu pos-homogeneous: e*lrelu(vec)
          s += p;
          hp = fmaf(p, vv, hp);
        }
      s += __shfl_xor(s, 16);   s += __shfl_xor(s, 32);
      hp += __shfl_xor(hp, 16); hp += __shfl_xor(hp, 32);
      if (lq == 0)
        out[(size_t)b * 512 + c] = (xh_ws[(size_t)b * 512 + c] + hp / s) * 0.5f;
    }
  }
}

extern "C" void kernel_launch(void* const* d_in, const int* in_sizes, int n_in,
                              void* d_out, int out_size, void* d_ws, size_t ws_size,
                              hipStream_t stream) {
  const float* x   = (const float*)d_in[0];
  const float* y   = (const float*)d_in[1];
  const float* fcw = (const float*)d_in[2];
  const float* fcb = (const float*)d_in[3];
  const float* qw  = (const float*)d_in[4];
  const float* qb  = (const float*)d_in[5];
  const float* kw  = (const float*)d_in[6];
  const float* kb  = (const float*)d_in[7];
  const float* vw  = (const float*)d_in[8];
  const float* vb  = (const float*)d_in[9];
  float* out = (float*)d_out;

  // ws: fcw_bf qw_bf kw_bf vw_bf (4 x 512KB u16) | xh_ws (4MB f32) | q_ws (4MB)
  u16* fcw_bf = (u16*)d_ws;
  u16* qw_bf  = fcw_bf + 262144;
  u16* kw_bf  = qw_bf + 262144;
  u16* vw_bf  = kw_bf + 262144;
  float* xh_ws = (float*)(vw_bf + 262144);
  float* q_ws  = xh_ws + (size_t)2048 * 512;

  convert_weights<<<1024, 256, 0, stream>>>(fcw, qw, kw, vw, fcw_bf);

  const size_t lds_bytes = 128 * XH_STRIDE * sizeof(u16);  // 133120 B
  hipFuncSetAttribute((const void*)xh_query,
                      hipFuncAttributeMaxDynamicSharedMemorySize, (int)lds_bytes);
  xh_query<<<16, 512, lds_bytes, stream>>>(x, fcw_bf, qw_bf, fcb, qb, xh_ws, q_ws);

  hipFuncSetAttribute((const void*)attn_main,
                      hipFuncAttributeMaxDynamicSharedMemorySize, (int)lds_bytes);
  attn_main<<<2048, 512, lds_bytes, stream>>>(y, fcw_bf, kw_bf, vw_bf, fcb, kb, vb,
                                              xh_ws, q_ws, out);
}